// Round 5
// baseline (1284.889 us; speedup 1.0000x reference)
//
#include <hip/hip_runtime.h>
#include <cstdint>

#define BB 64
#define SS 512
#define HH 512
#define EE 512
#define BSH (BB*SS*HH)

typedef _Float16 f16x8 __attribute__((ext_vector_type(8)));
typedef float    f32x4 __attribute__((ext_vector_type(4)));
typedef int      iv4   __attribute__((ext_vector_type(4)));
typedef unsigned long long u64;

__device__ __forceinline__ float tanh_fast(float x) {
    float e = __expf(2.0f * x);
    return 1.0f - 2.0f / (e + 1.0f);
}
__device__ __forceinline__ f16x8 pack8(float4 u, float4 v) {
    f16x8 h;
    h[0] = (_Float16)u.x; h[1] = (_Float16)u.y;
    h[2] = (_Float16)u.z; h[3] = (_Float16)u.w;
    h[4] = (_Float16)v.x; h[5] = (_Float16)v.y;
    h[6] = (_Float16)v.z; h[7] = (_Float16)v.w;
    return h;
}

// W scale: |W| <= 1/sqrt(512); map to [-127,127]
#define SW (127.0f * 22.627416997969522f)

__device__ __forceinline__ int quanw(float x) {
    return (int)rintf(fminf(fmaxf(x * SW, -127.0f), 127.0f));
}
__device__ __forceinline__ int packw4(float4 f) {
    int q0 = quanw(f.x), q1 = quanw(f.y), q2 = quanw(f.z), q3 = quanw(f.w);
    return (q0 & 255) | ((q1 & 255) << 8) | ((q2 & 255) << 16) | (q3 << 24);
}

// ---------------- Phase 1 (unchanged from R4): xp = W_ih @ emb[idx] + b_ih + b_hh
// into d_out outputs region; phase 2 reads xp, overwrites with h in-place.
__global__ __launch_bounds__(256, 3) void phase1(
    const int* __restrict__ idx, const float* __restrict__ emb,
    const float* __restrict__ Wih, const float* __restrict__ bih,
    const float* __restrict__ bhh, float* __restrict__ out) {
    __shared__ __align__(16) _Float16 Al[128 * 72];
    __shared__ __align__(16) _Float16 Bl[128 * 72];

    const int tid  = threadIdx.x;
    const int m0   = (blockIdx.x >> 2) * 128;
    const int n0   = (blockIdx.x & 3) * 128;
    const int wv   = tid >> 6;
    const int lane = tid & 63;
    const int n    = lane & 15;
    const int quad = lane >> 4;
    const int mw   = wv >> 1;
    const int nw   = wv & 1;

    const int sr = tid >> 1;
    const int kh = (tid & 1) * 32;
    const int rowidx = idx[m0 + sr];
    const float* ap = emb + (size_t)rowidx * EE + kh;
    const float* bp = Wih + (size_t)(n0 + sr) * EE + kh;

    f32x4 acc[4][4];
#pragma unroll
    for (int a = 0; a < 4; ++a)
#pragma unroll
        for (int c = 0; c < 4; ++c) acc[a][c] = (f32x4){0.f, 0.f, 0.f, 0.f};

    for (int kc = 0; kc < 8; ++kc) {
#pragma unroll
        for (int q = 0; q < 4; ++q) {
            float4 u = *(const float4*)(ap + kc * 64 + q * 8);
            float4 v = *(const float4*)(ap + kc * 64 + q * 8 + 4);
            *(f16x8*)&Al[sr * 72 + kh + q * 8] = pack8(u, v);
        }
#pragma unroll
        for (int q = 0; q < 4; ++q) {
            float4 u = *(const float4*)(bp + kc * 64 + q * 8);
            float4 v = *(const float4*)(bp + kc * 64 + q * 8 + 4);
            *(f16x8*)&Bl[sr * 72 + kh + q * 8] = pack8(u, v);
        }
        __syncthreads();

#pragma unroll
        for (int kk = 0; kk < 2; ++kk) {
            f16x8 bfr[4];
#pragma unroll
            for (int nb = 0; nb < 4; ++nb)
                bfr[nb] = *(const f16x8*)&Bl[(nw * 64 + nb * 16 + n) * 72 + kk * 32 + quad * 8];
#pragma unroll
            for (int mb = 0; mb < 4; ++mb) {
                f16x8 afr = *(const f16x8*)&Al[(mw * 64 + mb * 16 + n) * 72 + kk * 32 + quad * 8];
#pragma unroll
                for (int nb = 0; nb < 4; ++nb)
                    acc[mb][nb] = __builtin_amdgcn_mfma_f32_16x16x32_f16(
                        afr, bfr[nb], acc[mb][nb], 0, 0, 0);
            }
        }
        __syncthreads();
    }

    int   cc[4];
    float bv[4];
#pragma unroll
    for (int nb = 0; nb < 4; ++nb) {
        cc[nb] = n0 + nw * 64 + nb * 16 + n;
        bv[nb] = bih[cc[nb]] + bhh[cc[nb]];
    }
#pragma unroll
    for (int mb = 0; mb < 4; ++mb) {
        int rowg = m0 + mw * 64 + mb * 16 + quad * 4;
#pragma unroll
        for (int nb = 0; nb < 4; ++nb) {
#pragma unroll
            for (int i = 0; i < 4; ++i)
                out[(size_t)(rowg + i) * HH + cc[nb]] = acc[mb][nb][i] + bv[nb];
        }
    }
}

// ---------------- Phase 2: int8 MFMA recurrence, W fully register-resident.
// 4 WGs x 16 batches, 1024 thr (16 waves x 32 rows -> 4 waves/SIMD for latency
// hiding). W_hh i8: 64 VGPRs/lane. h image: i8, 8 KB, ping-pong. Per wave per
// step: 8x ds_read_b128 + 16x mfma_i32_16x16x64_i8 + 8-value tanh epilogue.
// Barrier = s_waitcnt lgkmcnt(0) + s_barrier (NO vmcnt drain: global h stores
// are thread-private output; the xp slot at t+1 is read only by its owner
// thread, which is also its only writer).
__global__ __launch_bounds__(1024) void phase2(
    const float* __restrict__ Whh, float* __restrict__ out) {
    __shared__ __align__(16) unsigned char himg[2][8192];  // ping-pong i8 h

    const int tid  = threadIdx.x;
    const int g    = blockIdx.x;        // batch group: batches g*16..+15
    const int wv   = tid >> 6;          // 0..15: rows wv*32..+31
    const int lane = tid & 63;
    const int n    = lane & 15;
    const int quad = lane >> 4;

    // A-fragments (i8, 16x16x64): A[m=lane&15][k=quad*16+j], j=0..15.
    iv4 areg[2][8];                     // 64 VGPRs
#pragma unroll
    for (int mb = 0; mb < 2; ++mb) {
        const float* wr = Whh + (size_t)(wv * 32 + mb * 16 + n) * HH + quad * 16;
#pragma unroll
        for (int kb = 0; kb < 8; ++kb) {
            const float4* p = (const float4*)(wr + kb * 64);
            iv4 v;
            v[0] = packw4(p[0]);
            v[1] = packw4(p[1]);
            v[2] = packw4(p[2]);
            v[3] = packw4(p[3]);
            areg[mb][kb] = v;
        }
    }
    ((u64*)himg[0])[tid] = 0;           // h0 = 0 (1024 thr x 8 B = 8 KB)
    __syncthreads();

    // output mapping (C/D layout): col n -> batch, row = quad*4 + reg
    const int b = g * 16 + n;
    float* obase = out + (size_t)b * (SS * HH);
    int r0[2], woff[2];
#pragma unroll
    for (int mb = 0; mb < 2; ++mb) {
        r0[mb] = wv * 32 + mb * 16 + quad * 4;
        // h-image addr for (k=r0..r0+3, n): (k>>6)*1024 + (((k>>4)&3)*16+n)*16 + (k&15)
        woff[mb] = ((r0[mb] >> 6) << 10) + ((((r0[mb] >> 4) & 3) * 16 + n) << 4)
                 + (r0[mb] & 15);
    }

    const float inv = 1.0f / (SW * 127.0f);

    float4 xpn[2];
#pragma unroll
    for (int mb = 0; mb < 2; ++mb) xpn[mb] = *(const float4*)(obase + r0[mb]);

    int cur = 0;
    for (int t = 0; t < SS; ++t) {
        float4 xp[2];
#pragma unroll
        for (int mb = 0; mb < 2; ++mb) xp[mb] = xpn[mb];
        if (t + 1 < SS) {   // prefetch next xp (hidden behind MFMA chain)
#pragma unroll
            for (int mb = 0; mb < 2; ++mb)
                xpn[mb] = *(const float4*)(obase + (size_t)(t + 1) * HH + r0[mb]);
        }

        iv4 acc[2];
#pragma unroll
        for (int mb = 0; mb < 2; ++mb) acc[mb] = (iv4){0, 0, 0, 0};

        const unsigned char* hbase = himg[cur] + lane * 16;
#pragma unroll
        for (int kb = 0; kb < 8; ++kb) {
            iv4 bfr = *(const iv4*)(hbase + (kb << 10));
#pragma unroll
            for (int mb = 0; mb < 2; ++mb)
                acc[mb] = __builtin_amdgcn_mfma_i32_16x16x64_i8(
                    areg[mb][kb], bfr, acc[mb], 0, 0, 0);
        }

        // epilogue: h = tanh(acc*inv + xp); f32 -> global, i8 -> next image
        unsigned char* wdst = himg[cur ^ 1];
#pragma unroll
        for (int mb = 0; mb < 2; ++mb) {
            float h0 = tanh_fast((float)acc[mb][0] * inv + xp[mb].x);
            float h1 = tanh_fast((float)acc[mb][1] * inv + xp[mb].y);
            float h2 = tanh_fast((float)acc[mb][2] * inv + xp[mb].z);
            float h3 = tanh_fast((float)acc[mb][3] * inv + xp[mb].w);
            *(float4*)(obase + (size_t)t * HH + r0[mb]) = make_float4(h0, h1, h2, h3);
            int q0 = (int)rintf(h0 * 127.0f);
            int q1 = (int)rintf(h1 * 127.0f);
            int q2 = (int)rintf(h2 * 127.0f);
            int q3 = (int)rintf(h3 * 127.0f);
            *(int*)(wdst + woff[mb]) =
                (q0 & 255) | ((q1 & 255) << 8) | ((q2 & 255) << 16) | (q3 << 24);
            if (t == SS - 1) {   // final hidden state
                *(float4*)(out + BSH + (size_t)b * HH + r0[mb]) =
                    make_float4(h0, h1, h2, h3);
            }
        }
        // barrier without vmcnt drain: only LDS (h-image) needs cross-wave order
        __builtin_amdgcn_s_waitcnt(0xC07F);  // vmcnt=63, expcnt=7, lgkmcnt=0
        __builtin_amdgcn_s_barrier();
        cur ^= 1;
    }
}

extern "C" void kernel_launch(void* const* d_in, const int* in_sizes, int n_in,
                              void* d_out, int out_size, void* d_ws, size_t ws_size,
                              hipStream_t stream) {
    const int*   idx = (const int*)d_in[0];
    const float* emb = (const float*)d_in[1];
    const float* Wih = (const float*)d_in[2];
    const float* Whh = (const float*)d_in[3];
    const float* bih = (const float*)d_in[4];
    const float* bhh = (const float*)d_in[5];
    float* out = (float*)d_out;

    phase1<<<dim3(1024), dim3(256), 0, stream>>>(idx, emb, Wih, bih, bhh, out);
    phase2<<<dim3(4), dim3(1024), 0, stream>>>(Whh, out);
}

// Round 6
// 729.272 us; speedup vs baseline: 1.7619x; 1.7619x over previous
//
#include <hip/hip_runtime.h>
#include <cstdint>

#define BB 64
#define SS 512
#define HH 512
#define EE 512
#define BSH (BB*SS*HH)

typedef _Float16 f16x8 __attribute__((ext_vector_type(8)));
typedef float    f32x4 __attribute__((ext_vector_type(4)));
typedef int      iv4   __attribute__((ext_vector_type(4)));
typedef unsigned long long u64;

__device__ __forceinline__ float tanh_fast(float x) {
    float e = __expf(2.0f * x);
    return 1.0f - 2.0f / (e + 1.0f);
}
__device__ __forceinline__ f16x8 pack8(float4 u, float4 v) {
    f16x8 h;
    h[0] = (_Float16)u.x; h[1] = (_Float16)u.y;
    h[2] = (_Float16)u.z; h[3] = (_Float16)u.w;
    h[4] = (_Float16)v.x; h[5] = (_Float16)v.y;
    h[6] = (_Float16)v.z; h[7] = (_Float16)v.w;
    return h;
}

// W scale: |W| <= 1/sqrt(512); map to [-127,127]
#define SW (127.0f * 22.627416997969522f)

__device__ __forceinline__ int quanw(float x) {
    return (int)rintf(fminf(fmaxf(x * SW, -127.0f), 127.0f));
}
__device__ __forceinline__ int packw4(float4 f) {
    int q0 = quanw(f.x), q1 = quanw(f.y), q2 = quanw(f.z), q3 = quanw(f.w);
    return (q0 & 255) | ((q1 & 255) << 8) | ((q2 & 255) << 16) | (q3 << 24);
}

// ---------------- Phase 1 (unchanged): xp = W_ih @ emb[idx] + b_ih + b_hh
// into d_out outputs region; phase 2 reads xp, overwrites with h in-place.
__global__ __launch_bounds__(256, 3) void phase1(
    const int* __restrict__ idx, const float* __restrict__ emb,
    const float* __restrict__ Wih, const float* __restrict__ bih,
    const float* __restrict__ bhh, float* __restrict__ out) {
    __shared__ __align__(16) _Float16 Al[128 * 72];
    __shared__ __align__(16) _Float16 Bl[128 * 72];

    const int tid  = threadIdx.x;
    const int m0   = (blockIdx.x >> 2) * 128;
    const int n0   = (blockIdx.x & 3) * 128;
    const int wv   = tid >> 6;
    const int lane = tid & 63;
    const int n    = lane & 15;
    const int quad = lane >> 4;
    const int mw   = wv >> 1;
    const int nw   = wv & 1;

    const int sr = tid >> 1;
    const int kh = (tid & 1) * 32;
    const int rowidx = idx[m0 + sr];
    const float* ap = emb + (size_t)rowidx * EE + kh;
    const float* bp = Wih + (size_t)(n0 + sr) * EE + kh;

    f32x4 acc[4][4];
#pragma unroll
    for (int a = 0; a < 4; ++a)
#pragma unroll
        for (int c = 0; c < 4; ++c) acc[a][c] = (f32x4){0.f, 0.f, 0.f, 0.f};

    for (int kc = 0; kc < 8; ++kc) {
#pragma unroll
        for (int q = 0; q < 4; ++q) {
            float4 u = *(const float4*)(ap + kc * 64 + q * 8);
            float4 v = *(const float4*)(ap + kc * 64 + q * 8 + 4);
            *(f16x8*)&Al[sr * 72 + kh + q * 8] = pack8(u, v);
        }
#pragma unroll
        for (int q = 0; q < 4; ++q) {
            float4 u = *(const float4*)(bp + kc * 64 + q * 8);
            float4 v = *(const float4*)(bp + kc * 64 + q * 8 + 4);
            *(f16x8*)&Bl[sr * 72 + kh + q * 8] = pack8(u, v);
        }
        __syncthreads();

#pragma unroll
        for (int kk = 0; kk < 2; ++kk) {
            f16x8 bfr[4];
#pragma unroll
            for (int nb = 0; nb < 4; ++nb)
                bfr[nb] = *(const f16x8*)&Bl[(nw * 64 + nb * 16 + n) * 72 + kk * 32 + quad * 8];
#pragma unroll
            for (int mb = 0; mb < 4; ++mb) {
                f16x8 afr = *(const f16x8*)&Al[(mw * 64 + mb * 16 + n) * 72 + kk * 32 + quad * 8];
#pragma unroll
                for (int nb = 0; nb < 4; ++nb)
                    acc[mb][nb] = __builtin_amdgcn_mfma_f32_16x16x32_f16(
                        afr, bfr[nb], acc[mb][nb], 0, 0, 0);
            }
        }
        __syncthreads();
    }

    int   cc[4];
    float bv[4];
#pragma unroll
    for (int nb = 0; nb < 4; ++nb) {
        cc[nb] = n0 + nw * 64 + nb * 16 + n;
        bv[nb] = bih[cc[nb]] + bhh[cc[nb]];
    }
#pragma unroll
    for (int mb = 0; mb < 4; ++mb) {
        int rowg = m0 + mw * 64 + mb * 16 + quad * 4;
#pragma unroll
        for (int nb = 0; nb < 4; ++nb) {
#pragma unroll
            for (int i = 0; i < 4; ++i)
                out[(size_t)(rowg + i) * HH + cc[nb]] = acc[mb][nb][i] + bv[nb];
        }
    }
}

// ---------------- Phase 2: int8 MFMA recurrence, 32 WGs x 2 batches.
// 512 thr = 8 waves x 64 rows; W_hh i8 register-resident (128 regs/lane).
// MFMA N=16 with only cols 0..1 valid (batch-parallel CU scaling beats MFMA
// efficiency: epilogue VALU was the bound). Valid lanes (n<2) dump raw i32
// accs to per-wave LDS scratch; all 64 lanes then process 2 h each
// (cvt+tanh+quant+stores) -- 8x less epilogue VALU per CU than R4.
// h image: [kb][col2][k64] i8, 1 KB ping-pong, 1 barrier/step.
__global__ __launch_bounds__(512, 2) void phase2(
    const float* __restrict__ Whh, float* __restrict__ out) {
    __shared__ __align__(16) unsigned char himg[2][1024];  // ping-pong i8 h
    __shared__ __align__(16) int cscr[8][160];             // per-wave compaction

    const int tid  = threadIdx.x;
    const int g    = blockIdx.x;        // batches 2g, 2g+1
    const int wv   = tid >> 6;          // 0..7: rows wv*64..+63
    const int lane = tid & 63;
    const int n    = lane & 15;
    const int quad = lane >> 4;

    // A-fragments (i8, 16x16x64): A[m=lane&15][k=quad*16+j], j=0..15.
    iv4 areg[4][8];                     // 128 regs
#pragma unroll
    for (int mb = 0; mb < 4; ++mb) {
        const float* wr = Whh + (size_t)(wv * 64 + mb * 16 + n) * HH + quad * 16;
#pragma unroll
        for (int kb = 0; kb < 8; ++kb) {
            const float4* p = (const float4*)(wr + kb * 64);
            iv4 v;
            v[0] = packw4(p[0]);
            v[1] = packw4(p[1]);
            v[2] = packw4(p[2]);
            v[3] = packw4(p[3]);
            areg[mb][kb] = v;
        }
    }
    if (tid < 128) ((u64*)himg[0])[tid] = 0;   // h0 = 0 (1 KB)
    __syncthreads();

    // Epilogue mapping: thread owns batch bp = lane>>5, rows row..row+1.
    const int bp  = lane >> 5;
    const int row = wv * 64 + (lane & 31) * 2;
    const int b   = g * 2 + bp;
    float* obase = out + (size_t)b * (SS * HH) + row;
    const int hwoff = wv * 128 + bp * 64 + (row & 63);   // [kb=wv][col=bp][k]
    // B-frag read base: [kb][col=n&1][k=quad*16+j]
    const unsigned char* hbase0 = himg[0] + (n & 1) * 64 + quad * 16;
    const unsigned char* hbase1 = himg[1] + (n & 1) * 64 + quad * 16;

    const float inv = 1.0f / (SW * 127.0f);

    float2 xpn = *(const float2*)obase;
    float hl0 = 0.f, hl1 = 0.f;
    int cur = 0;
    for (int t = 0; t < SS; ++t) {
        float2 xp = xpn;
        if (t + 1 < SS) xpn = *(const float2*)(obase + (size_t)(t + 1) * HH);

        iv4 acc[4];
#pragma unroll
        for (int mb = 0; mb < 4; ++mb) acc[mb] = (iv4){0, 0, 0, 0};

        const unsigned char* hb = cur ? hbase1 : hbase0;
#pragma unroll
        for (int kb = 0; kb < 8; ++kb) {
            iv4 bfr = *(const iv4*)(hb + (kb << 7));
#pragma unroll
            for (int mb = 0; mb < 4; ++mb)
                acc[mb] = __builtin_amdgcn_mfma_i32_16x16x64_i8(
                    areg[mb][kb], bfr, acc[mb], 0, 0, 0);
        }

        // wave-local compaction: valid lanes (n<2) dump raw i32 accs
        if (n < 2) {
#pragma unroll
            for (int mb = 0; mb < 4; ++mb)
                *(iv4*)&cscr[wv][n * 80 + mb * 16 + quad * 4] = acc[mb];
        }
        __asm__ volatile("s_waitcnt lgkmcnt(0)" ::: "memory");
        int zx = cscr[wv][bp * 80 + (lane & 31) * 2];
        int zy = cscr[wv][bp * 80 + (lane & 31) * 2 + 1];

        float h0 = tanh_fast((float)zx * inv + xp.x);
        float h1 = tanh_fast((float)zy * inv + xp.y);
        *(float2*)(obase + (size_t)t * HH) = make_float2(h0, h1);
        int q0 = (int)rintf(h0 * 127.0f);
        int q1 = (int)rintf(h1 * 127.0f);
        *(unsigned short*)(himg[cur ^ 1] + hwoff) =
            (unsigned short)((q0 & 255) | ((q1 & 255) << 8));
        hl0 = h0; hl1 = h1;
        __syncthreads();   // h_{t+1} image visible; ping-pong guards WAR
        cur ^= 1;
    }
    // final hidden state
    *(float2*)(out + BSH + (size_t)b * HH + row) = make_float2(hl0, hl1);
}

extern "C" void kernel_launch(void* const* d_in, const int* in_sizes, int n_in,
                              void* d_out, int out_size, void* d_ws, size_t ws_size,
                              hipStream_t stream) {
    const int*   idx = (const int*)d_in[0];
    const float* emb = (const float*)d_in[1];
    const float* Wih = (const float*)d_in[2];
    const float* Whh = (const float*)d_in[3];
    const float* bih = (const float*)d_in[4];
    const float* bhh = (const float*)d_in[5];
    float* out = (float*)d_out;

    phase1<<<dim3(1024), dim3(256), 0, stream>>>(idx, emb, Wih, bih, bhh, out);
    phase2<<<dim3(32), dim3(512), 0, stream>>>(Whh, out);
}